// Round 1
// baseline (930.586 us; speedup 1.0000x reference)
//
#include <hip/hip_runtime.h>

#define D 128

// ---------------- CSR build ----------------

__global__ __launch_bounds__(256) void count_kernel(const int* __restrict__ dst,
        int* __restrict__ counts, int E) {
    int e = blockIdx.x * 256 + threadIdx.x;
    if (e < E) atomicAdd(&counts[dst[e]], 1);
}

__global__ __launch_bounds__(1024) void scan_kernel(const int* __restrict__ counts,
        int* __restrict__ row_ptr, int* __restrict__ cursor, int n) {
    __shared__ int sdata[1024];
    int tid = threadIdx.x;
    int run = 0;
    for (int base = 0; base < n; base += 1024) {
        int i = base + tid;
        int v = (i < n) ? counts[i] : 0;
        sdata[tid] = v;
        __syncthreads();
        for (int off = 1; off < 1024; off <<= 1) {
            int t = (tid >= off) ? sdata[tid - off] : 0;
            __syncthreads();
            sdata[tid] += t;
            __syncthreads();
        }
        if (i < n) {
            int excl = run + sdata[tid] - v;
            row_ptr[i] = excl;
            cursor[i] = excl;
        }
        run += sdata[1023];
        __syncthreads();
    }
    if (tid == 0) row_ptr[n] = run;
}

__global__ __launch_bounds__(256) void fill_kernel(const int* __restrict__ src,
        const int* __restrict__ dst, int* __restrict__ cursor,
        int* __restrict__ src_sorted, int E) {
    int e = blockIdx.x * 256 + threadIdx.x;
    if (e < E) {
        int p = atomicAdd(&cursor[dst[e]], 1);
        src_sorted[p] = src[e];
    }
}

// ---------------- aggregation: out[node] = sum_{e: dst=node} h[src[e]] ----------------
// 8 nodes per 256-thread block; 32 lanes x float4 = full 128-f32 row per node.

__global__ __launch_bounds__(256) void agg_kernel(const float* __restrict__ h,
        const int* __restrict__ row_ptr, const int* __restrict__ src_sorted,
        float* __restrict__ out, int n) {
    int node = blockIdx.x * 8 + (threadIdx.x >> 5);
    int lane = threadIdx.x & 31;
    if (node >= n) return;
    int beg = row_ptr[node], end = row_ptr[node + 1];
    const float4* h4 = (const float4*)h;
    float4 acc = make_float4(0.f, 0.f, 0.f, 0.f);
    for (int j = beg; j < end; ++j) {
        int s = src_sorted[j];
        float4 v = h4[(size_t)s * 32 + lane];
        acc.x += v.x; acc.y += v.y; acc.z += v.z; acc.w += v.w;
    }
    ((float4*)out)[(size_t)node * 32 + lane] = acc;
}

// ---------------- O = relu(A @ W + b), A:[M,128], W:[128,128] ----------------
// Block = 256 threads covers 64 rows. Thread tile: 4 rows x 8 cols.
// W and A rows are tiny / heavily reused -> serve straight from L1/L2, no LDS.

__global__ __launch_bounds__(256) void gemm_relu(const float* __restrict__ A,
        const float* __restrict__ W, const float* __restrict__ bias,
        float* __restrict__ O, int M) {
    int tid = threadIdx.x;
    int rg = tid >> 4;         // 0..15
    int cg = tid & 15;         // 0..15
    int m0 = blockIdx.x * 64 + rg * 4;
    int c0 = cg * 8;
    float acc[4][8];
    #pragma unroll
    for (int r = 0; r < 4; ++r)
        #pragma unroll
        for (int j = 0; j < 8; ++j) acc[r][j] = 0.f;

    for (int k = 0; k < 128; k += 4) {
        float a[4][4];
        #pragma unroll
        for (int r = 0; r < 4; ++r) {
            int m = m0 + r;
            float4 v = (m < M) ? *(const float4*)&A[(size_t)m * 128 + k]
                               : make_float4(0.f, 0.f, 0.f, 0.f);
            a[r][0] = v.x; a[r][1] = v.y; a[r][2] = v.z; a[r][3] = v.w;
        }
        #pragma unroll
        for (int kk = 0; kk < 4; ++kk) {
            float4 w0 = *(const float4*)&W[(size_t)(k + kk) * 128 + c0];
            float4 w1 = *(const float4*)&W[(size_t)(k + kk) * 128 + c0 + 4];
            #pragma unroll
            for (int r = 0; r < 4; ++r) {
                float av = a[r][kk];
                acc[r][0] += av * w0.x; acc[r][1] += av * w0.y;
                acc[r][2] += av * w0.z; acc[r][3] += av * w0.w;
                acc[r][4] += av * w1.x; acc[r][5] += av * w1.y;
                acc[r][6] += av * w1.z; acc[r][7] += av * w1.w;
            }
        }
    }

    float4 bv0 = *(const float4*)&bias[c0];
    float4 bv1 = *(const float4*)&bias[c0 + 4];
    #pragma unroll
    for (int r = 0; r < 4; ++r) {
        int m = m0 + r;
        if (m < M) {
            float4 o0, o1;
            o0.x = fmaxf(acc[r][0] + bv0.x, 0.f);
            o0.y = fmaxf(acc[r][1] + bv0.y, 0.f);
            o0.z = fmaxf(acc[r][2] + bv0.z, 0.f);
            o0.w = fmaxf(acc[r][3] + bv0.w, 0.f);
            o1.x = fmaxf(acc[r][4] + bv1.x, 0.f);
            o1.y = fmaxf(acc[r][5] + bv1.y, 0.f);
            o1.z = fmaxf(acc[r][6] + bv1.z, 0.f);
            o1.w = fmaxf(acc[r][7] + bv1.w, 0.f);
            *(float4*)&O[(size_t)m * 128 + c0] = o0;
            *(float4*)&O[(size_t)m * 128 + c0 + 4] = o1;
        }
    }
}

// ---------------- s = mean(h, axis=0) ----------------

__global__ __launch_bounds__(128) void mean_kernel(const float* __restrict__ h,
        float* __restrict__ s, int n) {
    int t = threadIdx.x;
    float acc = 0.f;
    for (int r = blockIdx.x; r < n; r += gridDim.x)
        acc += h[(size_t)r * 128 + t];
    atomicAdd(&s[t], acc * (1.0f / 50000.0f));
}

// ---------------- wsv = Wd @ s ----------------

__global__ __launch_bounds__(128) void wd_kernel(const float* __restrict__ Wd,
        const float* __restrict__ s, float* __restrict__ wsv) {
    __shared__ float sl[128];
    int i = threadIdx.x;
    sl[i] = s[i];
    __syncthreads();
    float acc = 0.f;
    for (int j = 0; j < 128; ++j) acc += Wd[(size_t)i * 128 + j] * sl[j];
    wsv[i] = acc;
}

// ---------------- out[i] = dot(h[i], wsv), one wave per node ----------------

__global__ __launch_bounds__(256) void disc_kernel(const float* __restrict__ h,
        const float* __restrict__ wsv, float* __restrict__ out, int n) {
    int wave = threadIdx.x >> 6, lane = threadIdx.x & 63;
    int node = blockIdx.x * 4 + wave;
    if (node >= n) return;
    float2 hv = *(const float2*)&h[(size_t)node * 128 + lane * 2];
    float2 wv = *(const float2*)&wsv[lane * 2];
    float acc = hv.x * wv.x + hv.y * wv.y;
    #pragma unroll
    for (int off = 32; off > 0; off >>= 1) acc += __shfl_down(acc, off);
    if (lane == 0) out[node] = acc;
}

// ---------------- host orchestration ----------------

extern "C" void kernel_launch(void* const* d_in, const int* in_sizes, int n_in,
                              void* d_out, int out_size, void* d_ws, size_t ws_size,
                              hipStream_t stream) {
    const int* edge_index = (const int*)d_in[0];
    const float* x  = (const float*)d_in[1];
    const float* sx = (const float*)d_in[2];
    const float* W0 = (const float*)d_in[3];
    const float* b0 = (const float*)d_in[4];
    const float* W1 = (const float*)d_in[5];
    const float* b1 = (const float*)d_in[6];
    const float* W2 = (const float*)d_in[7];
    const float* b2 = (const float*)d_in[8];
    const float* Wd = (const float*)d_in[9];
    float* out = (float*)d_out;

    const int E = in_sizes[0] / 2;
    const int N = in_sizes[1] / D;
    const int* src = edge_index;
    const int* dst = edge_index + E;

    char* wsp = (char*)d_ws;
    size_t off = 0;
    auto alloc = [&](size_t bytes) -> void* {
        void* p = wsp + off;
        off += (bytes + 511) & ~(size_t)511;
        return p;
    };
    int* counts     = (int*)alloc((size_t)N * 4);
    int* row_ptr    = (int*)alloc((size_t)(N + 1) * 4);
    int* cursor     = (int*)alloc((size_t)N * 4);
    int* src_sorted = (int*)alloc((size_t)E * 4);
    float* svec     = (float*)alloc(D * 4);
    float* wsv      = (float*)alloc(D * 4);
    float* aggbuf   = (float*)alloc((size_t)N * D * 4);
    float* hbuf     = (float*)alloc((size_t)N * D * 4);

    hipMemsetAsync(counts, 0, (size_t)N * 4, stream);
    hipMemsetAsync(svec, 0, D * 4, stream);

    int eblocks = (E + 255) / 256;
    count_kernel<<<eblocks, 256, 0, stream>>>(dst, counts, E);
    scan_kernel<<<1, 1024, 0, stream>>>(counts, row_ptr, cursor, N);
    fill_kernel<<<eblocks, 256, 0, stream>>>(src, dst, cursor, src_sorted, E);

    int ablocks = (N + 7) / 8;
    int gblocks = (N + 63) / 64;

    auto encode = [&](const float* input) {
        agg_kernel<<<ablocks, 256, 0, stream>>>(input, row_ptr, src_sorted, aggbuf, N);
        gemm_relu<<<gblocks, 256, 0, stream>>>(aggbuf, W0, b0, hbuf, N);
        agg_kernel<<<ablocks, 256, 0, stream>>>(hbuf, row_ptr, src_sorted, aggbuf, N);
        gemm_relu<<<gblocks, 256, 0, stream>>>(aggbuf, W1, b1, hbuf, N);
        agg_kernel<<<ablocks, 256, 0, stream>>>(hbuf, row_ptr, src_sorted, aggbuf, N);
        gemm_relu<<<gblocks, 256, 0, stream>>>(aggbuf, W2, b2, hbuf, N);
    };

    // encode(x) -> h; summary; discriminator for h
    encode(x);
    mean_kernel<<<256, 128, 0, stream>>>(hbuf, svec, N);
    wd_kernel<<<1, 128, 0, stream>>>(Wd, svec, wsv);
    disc_kernel<<<(N + 3) / 4, 256, 0, stream>>>(hbuf, wsv, out, N);

    // encode(shuffled_x) -> shuffled_h (reuse hbuf); discriminator
    encode(sx);
    disc_kernel<<<(N + 3) / 4, 256, 0, stream>>>(hbuf, wsv, out + N, N);
}

// Round 2
// 818.779 us; speedup vs baseline: 1.1366x; 1.1366x over previous
//
#include <hip/hip_runtime.h>

#define D 128

// ---------------- CSR build ----------------

__global__ __launch_bounds__(256) void count_kernel(const int* __restrict__ dst,
        int* __restrict__ counts, int E) {
    int e = blockIdx.x * 256 + threadIdx.x;
    if (e < E) atomicAdd(&counts[dst[e]], 1);
}

// Phase 1: per-block (1024 elems) reduction of counts -> bsum[block]
__global__ __launch_bounds__(256) void scan_reduce(const int* __restrict__ counts,
        int* __restrict__ bsum, int n) {
    int b = blockIdx.x, t = threadIdx.x;
    int base = b * 1024 + t * 4;
    int s = 0;
    #pragma unroll
    for (int i = 0; i < 4; ++i) {
        int idx = base + i;
        if (idx < n) s += counts[idx];
    }
    __shared__ int sd[256];
    sd[t] = s;
    __syncthreads();
    #pragma unroll
    for (int off = 128; off > 0; off >>= 1) {
        if (t < off) sd[t] += sd[t + off];
        __syncthreads();
    }
    if (t == 0) bsum[b] = sd[0];
}

// Phase 2: single-wave exclusive scan of B (<=64) block sums; writes row_ptr[n]=total
__global__ __launch_bounds__(64) void scan_tops(const int* __restrict__ bsum,
        int* __restrict__ bofs, int* __restrict__ row_ptr_end, int B) {
    int t = threadIdx.x;
    int v = (t < B) ? bsum[t] : 0;
    int inc = v;
    #pragma unroll
    for (int off = 1; off < 64; off <<= 1) {
        int u = __shfl_up(inc, off);
        if (t >= off) inc += u;
    }
    if (t < B) bofs[t] = inc - v;
    if (t == 63) *row_ptr_end = inc;
}

// Phase 3: per-block exclusive scan of its 1024-chunk + block offset
__global__ __launch_bounds__(256) void scan_final(const int* __restrict__ counts,
        const int* __restrict__ bofs, int* __restrict__ row_ptr,
        int* __restrict__ cursor, int n) {
    int b = blockIdx.x, t = threadIdx.x;
    int base = b * 1024 + t * 4;
    int v[4];
    int s = 0;
    #pragma unroll
    for (int i = 0; i < 4; ++i) {
        int idx = base + i;
        v[i] = (idx < n) ? counts[idx] : 0;
        s += v[i];
    }
    __shared__ int sd[256];
    sd[t] = s;
    __syncthreads();
    #pragma unroll
    for (int off = 1; off < 256; off <<= 1) {
        int u = (t >= off) ? sd[t - off] : 0;
        __syncthreads();
        sd[t] += u;
        __syncthreads();
    }
    int excl = bofs[b] + sd[t] - s;
    #pragma unroll
    for (int i = 0; i < 4; ++i) {
        int idx = base + i;
        if (idx < n) {
            row_ptr[idx] = excl;
            cursor[idx] = excl;
            excl += v[i];
        }
    }
}

__global__ __launch_bounds__(256) void fill_kernel(const int* __restrict__ src,
        const int* __restrict__ dst, int* __restrict__ cursor,
        int* __restrict__ src_sorted, int E) {
    int e = blockIdx.x * 256 + threadIdx.x;
    if (e < E) {
        int p = atomicAdd(&cursor[dst[e]], 1);
        src_sorted[p] = src[e];
    }
}

// ---------------- aggregation: out[node] = sum_{e: dst=node} h[src[e]] ----------------
// 8 nodes per 256-thread block; 32 lanes x float4 = full 128-f32 row per node.
// Edge loop unrolled x2 for memory-level parallelism on the gather stream.

__global__ __launch_bounds__(256) void agg_kernel(const float* __restrict__ h,
        const int* __restrict__ row_ptr, const int* __restrict__ src_sorted,
        float* __restrict__ out, int n) {
    int node = blockIdx.x * 8 + (threadIdx.x >> 5);
    int lane = threadIdx.x & 31;
    if (node >= n) return;
    int beg = row_ptr[node], end = row_ptr[node + 1];
    const float4* h4 = (const float4*)h;
    float4 acc = make_float4(0.f, 0.f, 0.f, 0.f);
    int j = beg;
    for (; j + 1 < end; j += 2) {
        int s0 = src_sorted[j];
        int s1 = src_sorted[j + 1];
        float4 v0 = h4[(size_t)s0 * 32 + lane];
        float4 v1 = h4[(size_t)s1 * 32 + lane];
        acc.x += v0.x; acc.y += v0.y; acc.z += v0.z; acc.w += v0.w;
        acc.x += v1.x; acc.y += v1.y; acc.z += v1.z; acc.w += v1.w;
    }
    if (j < end) {
        int s0 = src_sorted[j];
        float4 v0 = h4[(size_t)s0 * 32 + lane];
        acc.x += v0.x; acc.y += v0.y; acc.z += v0.z; acc.w += v0.w;
    }
    ((float4*)out)[(size_t)node * 32 + lane] = acc;
}

// ---------------- O = relu(A @ W + b), A:[M,128], W:[128,128] ----------------
// Block = 256 threads covers 64 rows. Thread tile: 4 rows x 8 cols.

__global__ __launch_bounds__(256) void gemm_relu(const float* __restrict__ A,
        const float* __restrict__ W, const float* __restrict__ bias,
        float* __restrict__ O, int M) {
    int tid = threadIdx.x;
    int rg = tid >> 4;         // 0..15
    int cg = tid & 15;         // 0..15
    int m0 = blockIdx.x * 64 + rg * 4;
    int c0 = cg * 8;
    float acc[4][8];
    #pragma unroll
    for (int r = 0; r < 4; ++r)
        #pragma unroll
        for (int j = 0; j < 8; ++j) acc[r][j] = 0.f;

    for (int k = 0; k < 128; k += 4) {
        float a[4][4];
        #pragma unroll
        for (int r = 0; r < 4; ++r) {
            int m = m0 + r;
            float4 v = (m < M) ? *(const float4*)&A[(size_t)m * 128 + k]
                               : make_float4(0.f, 0.f, 0.f, 0.f);
            a[r][0] = v.x; a[r][1] = v.y; a[r][2] = v.z; a[r][3] = v.w;
        }
        #pragma unroll
        for (int kk = 0; kk < 4; ++kk) {
            float4 w0 = *(const float4*)&W[(size_t)(k + kk) * 128 + c0];
            float4 w1 = *(const float4*)&W[(size_t)(k + kk) * 128 + c0 + 4];
            #pragma unroll
            for (int r = 0; r < 4; ++r) {
                float av = a[r][kk];
                acc[r][0] += av * w0.x; acc[r][1] += av * w0.y;
                acc[r][2] += av * w0.z; acc[r][3] += av * w0.w;
                acc[r][4] += av * w1.x; acc[r][5] += av * w1.y;
                acc[r][6] += av * w1.z; acc[r][7] += av * w1.w;
            }
        }
    }

    float4 bv0 = *(const float4*)&bias[c0];
    float4 bv1 = *(const float4*)&bias[c0 + 4];
    #pragma unroll
    for (int r = 0; r < 4; ++r) {
        int m = m0 + r;
        if (m < M) {
            float4 o0, o1;
            o0.x = fmaxf(acc[r][0] + bv0.x, 0.f);
            o0.y = fmaxf(acc[r][1] + bv0.y, 0.f);
            o0.z = fmaxf(acc[r][2] + bv0.z, 0.f);
            o0.w = fmaxf(acc[r][3] + bv0.w, 0.f);
            o1.x = fmaxf(acc[r][4] + bv1.x, 0.f);
            o1.y = fmaxf(acc[r][5] + bv1.y, 0.f);
            o1.z = fmaxf(acc[r][6] + bv1.z, 0.f);
            o1.w = fmaxf(acc[r][7] + bv1.w, 0.f);
            *(float4*)&O[(size_t)m * 128 + c0] = o0;
            *(float4*)&O[(size_t)m * 128 + c0 + 4] = o1;
        }
    }
}

// ---------------- s = mean(h, axis=0) ----------------

__global__ __launch_bounds__(128) void mean_kernel(const float* __restrict__ h,
        float* __restrict__ s, int n) {
    int t = threadIdx.x;
    float acc = 0.f;
    for (int r = blockIdx.x; r < n; r += gridDim.x)
        acc += h[(size_t)r * 128 + t];
    atomicAdd(&s[t], acc * (1.0f / 50000.0f));
}

// ---------------- wsv = Wd @ s ----------------

__global__ __launch_bounds__(128) void wd_kernel(const float* __restrict__ Wd,
        const float* __restrict__ s, float* __restrict__ wsv) {
    __shared__ float sl[128];
    int i = threadIdx.x;
    sl[i] = s[i];
    __syncthreads();
    float acc = 0.f;
    for (int j = 0; j < 128; ++j) acc += Wd[(size_t)i * 128 + j] * sl[j];
    wsv[i] = acc;
}

// ---------------- out[i] = dot(h[i], wsv), one wave per node ----------------

__global__ __launch_bounds__(256) void disc_kernel(const float* __restrict__ h,
        const float* __restrict__ wsv, float* __restrict__ out, int n) {
    int wave = threadIdx.x >> 6, lane = threadIdx.x & 63;
    int node = blockIdx.x * 4 + wave;
    if (node >= n) return;
    float2 hv = *(const float2*)&h[(size_t)node * 128 + lane * 2];
    float2 wv = *(const float2*)&wsv[lane * 2];
    float acc = hv.x * wv.x + hv.y * wv.y;
    #pragma unroll
    for (int off = 32; off > 0; off >>= 1) acc += __shfl_down(acc, off);
    if (lane == 0) out[node] = acc;
}

// ---------------- host orchestration ----------------

extern "C" void kernel_launch(void* const* d_in, const int* in_sizes, int n_in,
                              void* d_out, int out_size, void* d_ws, size_t ws_size,
                              hipStream_t stream) {
    const int* edge_index = (const int*)d_in[0];
    const float* x  = (const float*)d_in[1];
    const float* sx = (const float*)d_in[2];
    const float* W0 = (const float*)d_in[3];
    const float* b0 = (const float*)d_in[4];
    const float* W1 = (const float*)d_in[5];
    const float* b1 = (const float*)d_in[6];
    const float* W2 = (const float*)d_in[7];
    const float* b2 = (const float*)d_in[8];
    const float* Wd = (const float*)d_in[9];
    float* out = (float*)d_out;

    const int E = in_sizes[0] / 2;
    const int N = in_sizes[1] / D;
    const int* src = edge_index;
    const int* dst = edge_index + E;

    char* wsp = (char*)d_ws;
    size_t off = 0;
    auto alloc = [&](size_t bytes) -> void* {
        void* p = wsp + off;
        off += (bytes + 511) & ~(size_t)511;
        return p;
    };
    int* counts     = (int*)alloc((size_t)N * 4);
    int* row_ptr    = (int*)alloc((size_t)(N + 1) * 4);
    int* cursor     = (int*)alloc((size_t)N * 4);
    int* src_sorted = (int*)alloc((size_t)E * 4);
    int* bsum       = (int*)alloc(64 * 4);
    int* bofs       = (int*)alloc(64 * 4);
    float* svec     = (float*)alloc(D * 4);
    float* wsv      = (float*)alloc(D * 4);
    float* aggbuf   = (float*)alloc((size_t)N * D * 4);
    float* hbuf     = (float*)alloc((size_t)N * D * 4);

    hipMemsetAsync(counts, 0, (size_t)N * 4, stream);
    hipMemsetAsync(svec, 0, D * 4, stream);

    int eblocks = (E + 255) / 256;
    int sblocks = (N + 1023) / 1024;   // 49 for N=50000
    count_kernel<<<eblocks, 256, 0, stream>>>(dst, counts, E);
    scan_reduce<<<sblocks, 256, 0, stream>>>(counts, bsum, N);
    scan_tops<<<1, 64, 0, stream>>>(bsum, bofs, row_ptr + N, sblocks);
    scan_final<<<sblocks, 256, 0, stream>>>(counts, bofs, row_ptr, cursor, N);
    fill_kernel<<<eblocks, 256, 0, stream>>>(src, dst, cursor, src_sorted, E);

    int ablocks = (N + 7) / 8;
    int gblocks = (N + 63) / 64;

    auto encode = [&](const float* input) {
        agg_kernel<<<ablocks, 256, 0, stream>>>(input, row_ptr, src_sorted, aggbuf, N);
        gemm_relu<<<gblocks, 256, 0, stream>>>(aggbuf, W0, b0, hbuf, N);
        agg_kernel<<<ablocks, 256, 0, stream>>>(hbuf, row_ptr, src_sorted, aggbuf, N);
        gemm_relu<<<gblocks, 256, 0, stream>>>(aggbuf, W1, b1, hbuf, N);
        agg_kernel<<<ablocks, 256, 0, stream>>>(hbuf, row_ptr, src_sorted, aggbuf, N);
        gemm_relu<<<gblocks, 256, 0, stream>>>(aggbuf, W2, b2, hbuf, N);
    };

    // encode(x) -> h; summary; discriminator for h
    encode(x);
    mean_kernel<<<256, 128, 0, stream>>>(hbuf, svec, N);
    wd_kernel<<<1, 128, 0, stream>>>(Wd, svec, wsv);
    disc_kernel<<<(N + 3) / 4, 256, 0, stream>>>(hbuf, wsv, out, N);

    // encode(shuffled_x) -> shuffled_h (reuse hbuf); discriminator
    encode(sx);
    disc_kernel<<<(N + 3) / 4, 256, 0, stream>>>(hbuf, wsv, out + N, N);
}

// Round 3
// 518.571 us; speedup vs baseline: 1.7945x; 1.5789x over previous
//
#include <hip/hip_runtime.h>

#define D 128

// bf16 helpers (finite values; RNE rounding)
static __device__ __forceinline__ unsigned short f2bf(float f) {
    unsigned int u = __float_as_uint(f);
    u = u + 0x7FFFu + ((u >> 16) & 1u);
    return (unsigned short)(u >> 16);
}
static __device__ __forceinline__ float bf2f(unsigned short h) {
    return __uint_as_float(((unsigned int)h) << 16);
}

// ---------------- CSR build ----------------

__global__ __launch_bounds__(256) void count_kernel(const int* __restrict__ dst,
        int* __restrict__ counts, int E) {
    int e = blockIdx.x * 256 + threadIdx.x;
    if (e < E) atomicAdd(&counts[dst[e]], 1);
}

__global__ __launch_bounds__(256) void scan_reduce(const int* __restrict__ counts,
        int* __restrict__ bsum, int n) {
    int b = blockIdx.x, t = threadIdx.x;
    int base = b * 1024 + t * 4;
    int s = 0;
    #pragma unroll
    for (int i = 0; i < 4; ++i) {
        int idx = base + i;
        if (idx < n) s += counts[idx];
    }
    __shared__ int sd[256];
    sd[t] = s;
    __syncthreads();
    #pragma unroll
    for (int off = 128; off > 0; off >>= 1) {
        if (t < off) sd[t] += sd[t + off];
        __syncthreads();
    }
    if (t == 0) bsum[b] = sd[0];
}

__global__ __launch_bounds__(64) void scan_tops(const int* __restrict__ bsum,
        int* __restrict__ bofs, int* __restrict__ row_ptr_end, int B) {
    int t = threadIdx.x;
    int v = (t < B) ? bsum[t] : 0;
    int inc = v;
    #pragma unroll
    for (int off = 1; off < 64; off <<= 1) {
        int u = __shfl_up(inc, off);
        if (t >= off) inc += u;
    }
    if (t < B) bofs[t] = inc - v;
    if (t == 63) *row_ptr_end = inc;
}

__global__ __launch_bounds__(256) void scan_final(const int* __restrict__ counts,
        const int* __restrict__ bofs, int* __restrict__ row_ptr,
        int* __restrict__ cursor, int n) {
    int b = blockIdx.x, t = threadIdx.x;
    int base = b * 1024 + t * 4;
    int v[4];
    int s = 0;
    #pragma unroll
    for (int i = 0; i < 4; ++i) {
        int idx = base + i;
        v[i] = (idx < n) ? counts[idx] : 0;
        s += v[i];
    }
    __shared__ int sd[256];
    sd[t] = s;
    __syncthreads();
    #pragma unroll
    for (int off = 1; off < 256; off <<= 1) {
        int u = (t >= off) ? sd[t - off] : 0;
        __syncthreads();
        sd[t] += u;
        __syncthreads();
    }
    int excl = bofs[b] + sd[t] - s;
    #pragma unroll
    for (int i = 0; i < 4; ++i) {
        int idx = base + i;
        if (idx < n) {
            row_ptr[idx] = excl;
            cursor[idx] = excl;
            excl += v[i];
        }
    }
}

__global__ __launch_bounds__(256) void fill_kernel(const int* __restrict__ src,
        const int* __restrict__ dst, int* __restrict__ cursor,
        int* __restrict__ src_sorted, int E) {
    int e = blockIdx.x * 256 + threadIdx.x;
    if (e < E) {
        int p = atomicAdd(&cursor[dst[e]], 1);
        src_sorted[p] = src[e];
    }
}

// ---------------- f32 -> bf16 bulk convert ----------------

__global__ __launch_bounds__(256) void cvt_kernel(const float* __restrict__ in,
        unsigned short* __restrict__ out, int n4) {
    int i = blockIdx.x * 256 + threadIdx.x;
    if (i < n4) {
        float4 v = ((const float4*)in)[i];
        ushort4 o;
        o.x = f2bf(v.x); o.y = f2bf(v.y); o.z = f2bf(v.z); o.w = f2bf(v.w);
        ((ushort4*)out)[i] = o;
    }
}

// ---------------- aggregation: out[node] = sum_{e: dst=node} h[src[e]] ----------------
// h is bf16 [N,128] (256 B rows). 8 nodes per 256-thread block; 32 lanes x 4 bf16.
// Accumulate f32, write f32.

__global__ __launch_bounds__(256) void agg_kernel(const unsigned short* __restrict__ h,
        const int* __restrict__ row_ptr, const int* __restrict__ src_sorted,
        float* __restrict__ out, int n) {
    int node = blockIdx.x * 8 + (threadIdx.x >> 5);
    int lane = threadIdx.x & 31;
    if (node >= n) return;
    int beg = row_ptr[node], end = row_ptr[node + 1];
    const ushort4* h4 = (const ushort4*)h;
    float4 acc = make_float4(0.f, 0.f, 0.f, 0.f);
    int j = beg;
    for (; j + 1 < end; j += 2) {
        int s0 = src_sorted[j];
        int s1 = src_sorted[j + 1];
        ushort4 v0 = h4[(size_t)s0 * 32 + lane];
        ushort4 v1 = h4[(size_t)s1 * 32 + lane];
        acc.x += bf2f(v0.x); acc.y += bf2f(v0.y); acc.z += bf2f(v0.z); acc.w += bf2f(v0.w);
        acc.x += bf2f(v1.x); acc.y += bf2f(v1.y); acc.z += bf2f(v1.z); acc.w += bf2f(v1.w);
    }
    if (j < end) {
        int s0 = src_sorted[j];
        ushort4 v0 = h4[(size_t)s0 * 32 + lane];
        acc.x += bf2f(v0.x); acc.y += bf2f(v0.y); acc.z += bf2f(v0.z); acc.w += bf2f(v0.w);
    }
    ((float4*)out)[(size_t)node * 32 + lane] = acc;
}

// ---------------- O_bf16 = relu(A @ W + b), A:[M,128] f32, W:[128,128] f32 ----------------
// 128 rows per 256-thread block. Thread tile: 8 rows x 8 cols (cols split c and c+64
// so each wave reads 16 contiguous 16B LDS chunks -> 2-way bank aliasing = free).
// W staged in LDS (64 KB -> 2 blocks/CU). A served from L1 (2 KB working set per k-chunk).

__global__ __launch_bounds__(256) void gemm_relu(const float* __restrict__ A,
        const float* __restrict__ W, const float* __restrict__ bias,
        unsigned short* __restrict__ O, int M) {
    __shared__ float Ws[128 * 128];
    int tid = threadIdx.x;

    // stage W (flat copy, coalesced float4)
    {
        const float4* W4 = (const float4*)W;
        float4* Ws4 = (float4*)Ws;
        #pragma unroll
        for (int i = 0; i < 16; ++i) Ws4[tid + i * 256] = W4[tid + i * 256];
    }
    __syncthreads();

    int rg = tid >> 4;           // 0..15
    int cg = tid & 15;           // 0..15
    int m0 = blockIdx.x * 128 + rg * 8;
    int cA = cg * 4;             // cols cA..cA+3
    int cB = 64 + cg * 4;        // cols cB..cB+3

    float accA[8][4], accB[8][4];
    #pragma unroll
    for (int r = 0; r < 8; ++r)
        #pragma unroll
        for (int j = 0; j < 4; ++j) { accA[r][j] = 0.f; accB[r][j] = 0.f; }

    const float4* A4 = (const float4*)A;
    for (int k = 0; k < 128; k += 4) {
        float4 a[8];
        #pragma unroll
        for (int r = 0; r < 8; ++r) {
            int mr = m0 + r; if (mr >= M) mr = M - 1;
            a[r] = A4[(size_t)mr * 32 + (k >> 2)];
        }
        #pragma unroll
        for (int kk = 0; kk < 4; ++kk) {
            float4 wa = *(const float4*)&Ws[(k + kk) * 128 + cA];
            float4 wb = *(const float4*)&Ws[(k + kk) * 128 + cB];
            #pragma unroll
            for (int r = 0; r < 8; ++r) {
                float av = (&a[r].x)[kk];
                accA[r][0] += av * wa.x; accA[r][1] += av * wa.y;
                accA[r][2] += av * wa.z; accA[r][3] += av * wa.w;
                accB[r][0] += av * wb.x; accB[r][1] += av * wb.y;
                accB[r][2] += av * wb.z; accB[r][3] += av * wb.w;
            }
        }
    }

    float4 ba = *(const float4*)&bias[cA];
    float4 bb = *(const float4*)&bias[cB];
    #pragma unroll
    for (int r = 0; r < 8; ++r) {
        int m = m0 + r;
        if (m < M) {
            ushort4 oa, ob;
            oa.x = f2bf(fmaxf(accA[r][0] + ba.x, 0.f));
            oa.y = f2bf(fmaxf(accA[r][1] + ba.y, 0.f));
            oa.z = f2bf(fmaxf(accA[r][2] + ba.z, 0.f));
            oa.w = f2bf(fmaxf(accA[r][3] + ba.w, 0.f));
            ob.x = f2bf(fmaxf(accB[r][0] + bb.x, 0.f));
            ob.y = f2bf(fmaxf(accB[r][1] + bb.y, 0.f));
            ob.z = f2bf(fmaxf(accB[r][2] + bb.z, 0.f));
            ob.w = f2bf(fmaxf(accB[r][3] + bb.w, 0.f));
            *(ushort4*)&O[(size_t)m * 128 + cA] = oa;
            *(ushort4*)&O[(size_t)m * 128 + cB] = ob;
        }
    }
}

// ---------------- s = mean(h, axis=0), h bf16 ----------------

__global__ __launch_bounds__(128) void mean_kernel(const unsigned short* __restrict__ h,
        float* __restrict__ s, int n) {
    int t = threadIdx.x;
    float acc = 0.f;
    for (int r = blockIdx.x; r < n; r += gridDim.x)
        acc += bf2f(h[(size_t)r * 128 + t]);
    atomicAdd(&s[t], acc * (1.0f / 50000.0f));
}

// ---------------- wsv = Wd @ s ----------------

__global__ __launch_bounds__(128) void wd_kernel(const float* __restrict__ Wd,
        const float* __restrict__ s, float* __restrict__ wsv) {
    __shared__ float sl[128];
    int i = threadIdx.x;
    sl[i] = s[i];
    __syncthreads();
    float acc = 0.f;
    for (int j = 0; j < 128; ++j) acc += Wd[(size_t)i * 128 + j] * sl[j];
    wsv[i] = acc;
}

// ---------------- out[i] = dot(h[i], wsv), h bf16, one wave per node ----------------

__global__ __launch_bounds__(256) void disc_kernel(const unsigned short* __restrict__ h,
        const float* __restrict__ wsv, float* __restrict__ out, int n) {
    int wave = threadIdx.x >> 6, lane = threadIdx.x & 63;
    int node = blockIdx.x * 4 + wave;
    if (node >= n) return;
    unsigned int hv = ((const unsigned int*)h)[(size_t)node * 64 + lane];
    float2 wv = *(const float2*)&wsv[lane * 2];
    float lo = __uint_as_float(hv << 16);
    float hi = __uint_as_float(hv & 0xFFFF0000u);
    float acc = lo * wv.x + hi * wv.y;
    #pragma unroll
    for (int off = 32; off > 0; off >>= 1) acc += __shfl_down(acc, off);
    if (lane == 0) out[node] = acc;
}

// ---------------- host orchestration ----------------

extern "C" void kernel_launch(void* const* d_in, const int* in_sizes, int n_in,
                              void* d_out, int out_size, void* d_ws, size_t ws_size,
                              hipStream_t stream) {
    const int* edge_index = (const int*)d_in[0];
    const float* x  = (const float*)d_in[1];
    const float* sx = (const float*)d_in[2];
    const float* W0 = (const float*)d_in[3];
    const float* b0 = (const float*)d_in[4];
    const float* W1 = (const float*)d_in[5];
    const float* b1 = (const float*)d_in[6];
    const float* W2 = (const float*)d_in[7];
    const float* b2 = (const float*)d_in[8];
    const float* Wd = (const float*)d_in[9];
    float* out = (float*)d_out;

    const int E = in_sizes[0] / 2;
    const int N = in_sizes[1] / D;
    const int* src = edge_index;
    const int* dst = edge_index + E;

    char* wsp = (char*)d_ws;
    size_t off = 0;
    auto alloc = [&](size_t bytes) -> void* {
        void* p = wsp + off;
        off += (bytes + 511) & ~(size_t)511;
        return p;
    };
    int* counts     = (int*)alloc((size_t)N * 4);
    int* row_ptr    = (int*)alloc((size_t)(N + 1) * 4);
    int* cursor     = (int*)alloc((size_t)N * 4);
    int* src_sorted = (int*)alloc((size_t)E * 4);
    int* bsum       = (int*)alloc(64 * 4);
    int* bofs       = (int*)alloc(64 * 4);
    float* svec     = (float*)alloc(D * 4);
    float* wsv      = (float*)alloc(D * 4);
    float* aggbuf          = (float*)alloc((size_t)N * D * 4);          // f32 agg output
    unsigned short* hbuf   = (unsigned short*)alloc((size_t)N * D * 2); // bf16 activations
    unsigned short* xbuf   = (unsigned short*)alloc((size_t)N * D * 2); // bf16 input (reused)

    hipMemsetAsync(counts, 0, (size_t)N * 4, stream);
    hipMemsetAsync(svec, 0, D * 4, stream);

    int eblocks = (E + 255) / 256;
    int sblocks = (N + 1023) / 1024;
    count_kernel<<<eblocks, 256, 0, stream>>>(dst, counts, E);
    scan_reduce<<<sblocks, 256, 0, stream>>>(counts, bsum, N);
    scan_tops<<<1, 64, 0, stream>>>(bsum, bofs, row_ptr + N, sblocks);
    scan_final<<<sblocks, 256, 0, stream>>>(counts, bofs, row_ptr, cursor, N);
    fill_kernel<<<eblocks, 256, 0, stream>>>(src, dst, cursor, src_sorted, E);

    int n4 = N * D / 4;
    int cblocks = (n4 + 255) / 256;
    int ablocks = (N + 7) / 8;
    int gblocks = (N + 127) / 128;

    auto encode = [&](const float* input) {
        cvt_kernel<<<cblocks, 256, 0, stream>>>(input, xbuf, n4);
        agg_kernel<<<ablocks, 256, 0, stream>>>(xbuf, row_ptr, src_sorted, aggbuf, N);
        gemm_relu<<<gblocks, 256, 0, stream>>>(aggbuf, W0, b0, hbuf, N);
        agg_kernel<<<ablocks, 256, 0, stream>>>(hbuf, row_ptr, src_sorted, aggbuf, N);
        gemm_relu<<<gblocks, 256, 0, stream>>>(aggbuf, W1, b1, hbuf, N);
        agg_kernel<<<ablocks, 256, 0, stream>>>(hbuf, row_ptr, src_sorted, aggbuf, N);
        gemm_relu<<<gblocks, 256, 0, stream>>>(aggbuf, W2, b2, hbuf, N);
    };

    // encode(x) -> h; summary; discriminator for h
    encode(x);
    mean_kernel<<<256, 128, 0, stream>>>(hbuf, svec, N);
    wd_kernel<<<1, 128, 0, stream>>>(Wd, svec, wsv);
    disc_kernel<<<(N + 3) / 4, 256, 0, stream>>>(hbuf, wsv, out, N);

    // encode(shuffled_x) -> shuffled_h (reuse hbuf); discriminator
    encode(sx);
    disc_kernel<<<(N + 3) / 4, 256, 0, stream>>>(hbuf, wsv, out + N, N);
}

// Round 4
// 406.225 us; speedup vs baseline: 2.2908x; 1.2766x over previous
//
#include <hip/hip_runtime.h>

#define D 128

// bf16 helpers (finite values; RNE rounding)
static __device__ __forceinline__ unsigned short f2bf(float f) {
    unsigned int u = __float_as_uint(f);
    u = u + 0x7FFFu + ((u >> 16) & 1u);
    return (unsigned short)(u >> 16);
}
static __device__ __forceinline__ float bf2f(unsigned short h) {
    return __uint_as_float(((unsigned int)h) << 16);
}

// ---------------- CSR build ----------------

__global__ __launch_bounds__(256) void count_kernel(const int* __restrict__ dst,
        int* __restrict__ counts, int E) {
    int e = blockIdx.x * 256 + threadIdx.x;
    if (e < E) atomicAdd(&counts[dst[e]], 1);
}

__global__ __launch_bounds__(256) void scan_reduce(const int* __restrict__ counts,
        int* __restrict__ bsum, int n) {
    int b = blockIdx.x, t = threadIdx.x;
    int base = b * 1024 + t * 4;
    int s = 0;
    #pragma unroll
    for (int i = 0; i < 4; ++i) {
        int idx = base + i;
        if (idx < n) s += counts[idx];
    }
    __shared__ int sd[256];
    sd[t] = s;
    __syncthreads();
    #pragma unroll
    for (int off = 128; off > 0; off >>= 1) {
        if (t < off) sd[t] += sd[t + off];
        __syncthreads();
    }
    if (t == 0) bsum[b] = sd[0];
}

__global__ __launch_bounds__(64) void scan_tops(const int* __restrict__ bsum,
        int* __restrict__ bofs, int* __restrict__ row_ptr_end, int B) {
    int t = threadIdx.x;
    int v = (t < B) ? bsum[t] : 0;
    int inc = v;
    #pragma unroll
    for (int off = 1; off < 64; off <<= 1) {
        int u = __shfl_up(inc, off);
        if (t >= off) inc += u;
    }
    if (t < B) bofs[t] = inc - v;
    if (t == 63) *row_ptr_end = inc;
}

__global__ __launch_bounds__(256) void scan_final(const int* __restrict__ counts,
        const int* __restrict__ bofs, int* __restrict__ row_ptr,
        int* __restrict__ cursor, int n) {
    int b = blockIdx.x, t = threadIdx.x;
    int base = b * 1024 + t * 4;
    int v[4];
    int s = 0;
    #pragma unroll
    for (int i = 0; i < 4; ++i) {
        int idx = base + i;
        v[i] = (idx < n) ? counts[idx] : 0;
        s += v[i];
    }
    __shared__ int sd[256];
    sd[t] = s;
    __syncthreads();
    #pragma unroll
    for (int off = 1; off < 256; off <<= 1) {
        int u = (t >= off) ? sd[t - off] : 0;
        __syncthreads();
        sd[t] += u;
        __syncthreads();
    }
    int excl = bofs[b] + sd[t] - s;
    #pragma unroll
    for (int i = 0; i < 4; ++i) {
        int idx = base + i;
        if (idx < n) {
            row_ptr[idx] = excl;
            cursor[idx] = excl;
            excl += v[i];
        }
    }
}

__global__ __launch_bounds__(256) void fill_kernel(const int* __restrict__ src,
        const int* __restrict__ dst, int* __restrict__ cursor,
        int* __restrict__ src_sorted, int E) {
    int e = blockIdx.x * 256 + threadIdx.x;
    if (e < E) {
        int p = atomicAdd(&cursor[dst[e]], 1);
        src_sorted[p] = src[e];
    }
}

// ---------------- f32 -> bf16 bulk convert ----------------

__global__ __launch_bounds__(256) void cvt_kernel(const float* __restrict__ in,
        unsigned short* __restrict__ out, int n4) {
    int i = blockIdx.x * 256 + threadIdx.x;
    if (i < n4) {
        float4 v = ((const float4*)in)[i];
        ushort4 o;
        o.x = f2bf(v.x); o.y = f2bf(v.y); o.z = f2bf(v.z); o.w = f2bf(v.w);
        ((ushort4*)out)[i] = o;
    }
}

// ---------------- aggregation (optionally batched over 2 graphs) ----------------
// h bf16 [NT,128]; nodes [0,N) use rows [0,N), nodes [N,NT) gather with +N offset.
// 16 lanes x uint4 (8 bf16) per node; 16 nodes per 256-thread block; unroll x4.

__global__ __launch_bounds__(256) void agg_kernel(const unsigned short* __restrict__ h,
        const int* __restrict__ row_ptr, const int* __restrict__ src_sorted,
        float* __restrict__ out, int N, int NT) {
    int node = blockIdx.x * 16 + (threadIdx.x >> 4);
    int lane = threadIdx.x & 15;
    if (node >= NT) return;
    int base = (node < N) ? 0 : N;
    int rp = node - base;
    int beg = row_ptr[rp], end = row_ptr[rp + 1];
    const uint4* h4 = (const uint4*)h;

    float acc[8];
    #pragma unroll
    for (int i = 0; i < 8; ++i) acc[i] = 0.f;

    auto addrow = [&](uint4 v) {
        acc[0] += __uint_as_float(v.x << 16);
        acc[1] += __uint_as_float(v.x & 0xFFFF0000u);
        acc[2] += __uint_as_float(v.y << 16);
        acc[3] += __uint_as_float(v.y & 0xFFFF0000u);
        acc[4] += __uint_as_float(v.z << 16);
        acc[5] += __uint_as_float(v.z & 0xFFFF0000u);
        acc[6] += __uint_as_float(v.w << 16);
        acc[7] += __uint_as_float(v.w & 0xFFFF0000u);
    };

    int j = beg;
    for (; j + 3 < end; j += 4) {
        int s0 = src_sorted[j] + base;
        int s1 = src_sorted[j + 1] + base;
        int s2 = src_sorted[j + 2] + base;
        int s3 = src_sorted[j + 3] + base;
        uint4 v0 = h4[(size_t)s0 * 16 + lane];
        uint4 v1 = h4[(size_t)s1 * 16 + lane];
        uint4 v2 = h4[(size_t)s2 * 16 + lane];
        uint4 v3 = h4[(size_t)s3 * 16 + lane];
        addrow(v0); addrow(v1); addrow(v2); addrow(v3);
    }
    for (; j < end; ++j) {
        int s0 = src_sorted[j] + base;
        addrow(h4[(size_t)s0 * 16 + lane]);
    }

    float4 f0 = make_float4(acc[0], acc[1], acc[2], acc[3]);
    float4 f1 = make_float4(acc[4], acc[5], acc[6], acc[7]);
    float4* o4 = (float4*)out;
    o4[(size_t)node * 32 + lane * 2]     = f0;
    o4[(size_t)node * 32 + lane * 2 + 1] = f1;
}

// ---------------- O_bf16 = relu(A @ W + b); optional fused column-mean ----------------
// 128 rows/block, thread tile 8x8 (cols c, c+64). W staged in LDS (64 KB).
// If mean_out != nullptr, also accumulates sum over rows m < Nmean of relu output
// into mean_out[c] (scaled by inv_n) via LDS reduction + 1 atomic per col per block.

__global__ __launch_bounds__(256) void gemm_relu(const float* __restrict__ A,
        const float* __restrict__ W, const float* __restrict__ bias,
        unsigned short* __restrict__ O, int M,
        float* __restrict__ mean_out, int Nmean, float inv_n) {
    __shared__ float Ws[128 * 128];
    __shared__ float red[16][128];
    int tid = threadIdx.x;

    {
        const float4* W4 = (const float4*)W;
        float4* Ws4 = (float4*)Ws;
        #pragma unroll
        for (int i = 0; i < 16; ++i) Ws4[tid + i * 256] = W4[tid + i * 256];
    }
    __syncthreads();

    int rg = tid >> 4;           // 0..15
    int cg = tid & 15;           // 0..15
    int m0 = blockIdx.x * 128 + rg * 8;
    int cA = cg * 4;
    int cB = 64 + cg * 4;

    float accA[8][4], accB[8][4];
    #pragma unroll
    for (int r = 0; r < 8; ++r)
        #pragma unroll
        for (int j = 0; j < 4; ++j) { accA[r][j] = 0.f; accB[r][j] = 0.f; }

    const float4* A4 = (const float4*)A;
    for (int k = 0; k < 128; k += 4) {
        float4 a[8];
        #pragma unroll
        for (int r = 0; r < 8; ++r) {
            int mr = m0 + r; if (mr >= M) mr = M - 1;
            a[r] = A4[(size_t)mr * 32 + (k >> 2)];
        }
        #pragma unroll
        for (int kk = 0; kk < 4; ++kk) {
            float4 wa = *(const float4*)&Ws[(k + kk) * 128 + cA];
            float4 wb = *(const float4*)&Ws[(k + kk) * 128 + cB];
            #pragma unroll
            for (int r = 0; r < 8; ++r) {
                float av = (&a[r].x)[kk];
                accA[r][0] += av * wa.x; accA[r][1] += av * wa.y;
                accA[r][2] += av * wa.z; accA[r][3] += av * wa.w;
                accB[r][0] += av * wb.x; accB[r][1] += av * wb.y;
                accB[r][2] += av * wb.z; accB[r][3] += av * wb.w;
            }
        }
    }

    float4 ba = *(const float4*)&bias[cA];
    float4 bb = *(const float4*)&bias[cB];
    float psA[4] = {0.f, 0.f, 0.f, 0.f};
    float psB[4] = {0.f, 0.f, 0.f, 0.f};

    #pragma unroll
    for (int r = 0; r < 8; ++r) {
        int m = m0 + r;
        float vA[4], vB[4];
        vA[0] = fmaxf(accA[r][0] + ba.x, 0.f);
        vA[1] = fmaxf(accA[r][1] + ba.y, 0.f);
        vA[2] = fmaxf(accA[r][2] + ba.z, 0.f);
        vA[3] = fmaxf(accA[r][3] + ba.w, 0.f);
        vB[0] = fmaxf(accB[r][0] + bb.x, 0.f);
        vB[1] = fmaxf(accB[r][1] + bb.y, 0.f);
        vB[2] = fmaxf(accB[r][2] + bb.z, 0.f);
        vB[3] = fmaxf(accB[r][3] + bb.w, 0.f);
        if (m < M) {
            ushort4 oa, ob;
            oa.x = f2bf(vA[0]); oa.y = f2bf(vA[1]); oa.z = f2bf(vA[2]); oa.w = f2bf(vA[3]);
            ob.x = f2bf(vB[0]); ob.y = f2bf(vB[1]); ob.z = f2bf(vB[2]); ob.w = f2bf(vB[3]);
            *(ushort4*)&O[(size_t)m * 128 + cA] = oa;
            *(ushort4*)&O[(size_t)m * 128 + cB] = ob;
        }
        if (m < Nmean) {
            psA[0] += vA[0]; psA[1] += vA[1]; psA[2] += vA[2]; psA[3] += vA[3];
            psB[0] += vB[0]; psB[1] += vB[1]; psB[2] += vB[2]; psB[3] += vB[3];
        }
    }

    if (mean_out) {
        #pragma unroll
        for (int j = 0; j < 4; ++j) {
            red[rg][cA + j] = psA[j];
            red[rg][cB + j] = psB[j];
        }
        __syncthreads();
        if (tid < 128) {
            float s = 0.f;
            #pragma unroll
            for (int i = 0; i < 16; ++i) s += red[i][tid];
            if (s != 0.f) atomicAdd(&mean_out[tid], s * inv_n);
        }
    }
}

// ---------------- wsv = Wd @ s ----------------

__global__ __launch_bounds__(128) void wd_kernel(const float* __restrict__ Wd,
        const float* __restrict__ s, float* __restrict__ wsv) {
    __shared__ float sl[128];
    int i = threadIdx.x;
    sl[i] = s[i];
    __syncthreads();
    float acc = 0.f;
    for (int j = 0; j < 128; ++j) acc += Wd[(size_t)i * 128 + j] * sl[j];
    wsv[i] = acc;
}

// ---------------- out[i] = dot(h[i], wsv), h bf16, one wave per node ----------------

__global__ __launch_bounds__(256) void disc_kernel(const unsigned short* __restrict__ h,
        const float* __restrict__ wsv, float* __restrict__ out, int n) {
    int wave = threadIdx.x >> 6, lane = threadIdx.x & 63;
    int node = blockIdx.x * 4 + wave;
    if (node >= n) return;
    unsigned int hv = ((const unsigned int*)h)[(size_t)node * 64 + lane];
    float2 wv = *(const float2*)&wsv[lane * 2];
    float lo = __uint_as_float(hv << 16);
    float hi = __uint_as_float(hv & 0xFFFF0000u);
    float acc = lo * wv.x + hi * wv.y;
    #pragma unroll
    for (int off = 32; off > 0; off >>= 1) acc += __shfl_down(acc, off);
    if (lane == 0) out[node] = acc;
}

// ---------------- host orchestration ----------------

extern "C" void kernel_launch(void* const* d_in, const int* in_sizes, int n_in,
                              void* d_out, int out_size, void* d_ws, size_t ws_size,
                              hipStream_t stream) {
    const int* edge_index = (const int*)d_in[0];
    const float* x  = (const float*)d_in[1];
    const float* sx = (const float*)d_in[2];
    const float* W0 = (const float*)d_in[3];
    const float* b0 = (const float*)d_in[4];
    const float* W1 = (const float*)d_in[5];
    const float* b1 = (const float*)d_in[6];
    const float* W2 = (const float*)d_in[7];
    const float* b2 = (const float*)d_in[8];
    const float* Wd = (const float*)d_in[9];
    float* out = (float*)d_out;

    const int E = in_sizes[0] / 2;
    const int N = in_sizes[1] / D;
    const int* src = edge_index;
    const int* dst = edge_index + E;
    const float inv_n = 1.0f / (float)N;

    char* wsp = (char*)d_ws;
    size_t off = 0;
    auto alloc = [&](size_t bytes) -> void* {
        void* p = wsp + off;
        off += (bytes + 511) & ~(size_t)511;
        return p;
    };
    int* counts     = (int*)alloc((size_t)N * 4);
    int* row_ptr    = (int*)alloc((size_t)(N + 1) * 4);
    int* cursor     = (int*)alloc((size_t)N * 4);
    int* src_sorted = (int*)alloc((size_t)E * 4);
    int* bsum       = (int*)alloc(64 * 4);
    int* bofs       = (int*)alloc(64 * 4);
    float* svec     = (float*)alloc(D * 4);
    float* wsv      = (float*)alloc(D * 4);

    // remaining workspace decides batched (2N) vs sequential (N) path
    size_t fixed = off;
    size_t need_batched = fixed + ((size_t)2 * N * D * 4 + 512) + ((size_t)2 * N * D * 2 + 512);
    bool batched = ws_size >= need_batched;
    int NB = batched ? 2 * N : N;

    float* aggbuf        = (float*)alloc((size_t)NB * D * 4);
    unsigned short* hbuf = (unsigned short*)alloc((size_t)NB * D * 2); // also used as bf16 input

    hipMemsetAsync(counts, 0, (size_t)N * 4, stream);
    hipMemsetAsync(svec, 0, D * 4, stream);

    int eblocks = (E + 255) / 256;
    int sblocks = (N + 1023) / 1024;
    count_kernel<<<eblocks, 256, 0, stream>>>(dst, counts, E);
    scan_reduce<<<sblocks, 256, 0, stream>>>(counts, bsum, N);
    scan_tops<<<1, 64, 0, stream>>>(bsum, bofs, row_ptr + N, sblocks);
    scan_final<<<sblocks, 256, 0, stream>>>(counts, bofs, row_ptr, cursor, N);
    fill_kernel<<<eblocks, 256, 0, stream>>>(src, dst, cursor, src_sorted, E);

    int n4 = N * D / 4;
    int cblocks = (n4 + 255) / 256;
    int ablocks = (NB + 15) / 16;
    int gblocks = (NB + 127) / 128;

    if (batched) {
        // hbuf doubles as bf16 input buffer (consumed by first agg before layer-0 gemm writes it)
        cvt_kernel<<<cblocks, 256, 0, stream>>>(x, hbuf, n4);
        cvt_kernel<<<cblocks, 256, 0, stream>>>(sx, hbuf + (size_t)N * D, n4);
        agg_kernel<<<ablocks, 256, 0, stream>>>(hbuf, row_ptr, src_sorted, aggbuf, N, NB);
        gemm_relu<<<gblocks, 256, 0, stream>>>(aggbuf, W0, b0, hbuf, NB, nullptr, 0, 0.f);
        agg_kernel<<<ablocks, 256, 0, stream>>>(hbuf, row_ptr, src_sorted, aggbuf, N, NB);
        gemm_relu<<<gblocks, 256, 0, stream>>>(aggbuf, W1, b1, hbuf, NB, nullptr, 0, 0.f);
        agg_kernel<<<ablocks, 256, 0, stream>>>(hbuf, row_ptr, src_sorted, aggbuf, N, NB);
        gemm_relu<<<gblocks, 256, 0, stream>>>(aggbuf, W2, b2, hbuf, NB, svec, N, inv_n);
        wd_kernel<<<1, 128, 0, stream>>>(Wd, svec, wsv);
        disc_kernel<<<(NB + 3) / 4, 256, 0, stream>>>(hbuf, wsv, out, NB);
    } else {
        auto encode = [&](const float* input, float* mean_out) {
            cvt_kernel<<<cblocks, 256, 0, stream>>>(input, hbuf, n4);
            agg_kernel<<<ablocks, 256, 0, stream>>>(hbuf, row_ptr, src_sorted, aggbuf, N, NB);
            gemm_relu<<<gblocks, 256, 0, stream>>>(aggbuf, W0, b0, hbuf, NB, nullptr, 0, 0.f);
            agg_kernel<<<ablocks, 256, 0, stream>>>(hbuf, row_ptr, src_sorted, aggbuf, N, NB);
            gemm_relu<<<gblocks, 256, 0, stream>>>(aggbuf, W1, b1, hbuf, NB, nullptr, 0, 0.f);
            agg_kernel<<<ablocks, 256, 0, stream>>>(hbuf, row_ptr, src_sorted, aggbuf, N, NB);
            gemm_relu<<<gblocks, 256, 0, stream>>>(aggbuf, W2, b2, hbuf, NB, mean_out, mean_out ? N : 0, inv_n);
        };
        encode(x, svec);
        wd_kernel<<<1, 128, 0, stream>>>(Wd, svec, wsv);
        disc_kernel<<<(NB + 3) / 4, 256, 0, stream>>>(hbuf, wsv, out, NB);
        encode(sx, nullptr);
        disc_kernel<<<(NB + 3) / 4, 256, 0, stream>>>(hbuf, wsv, out + N, NB);
    }
}

// Round 5
// 365.578 us; speedup vs baseline: 2.5455x; 1.1112x over previous
//
#include <hip/hip_runtime.h>

#define D 128

typedef short bf16x8 __attribute__((ext_vector_type(8)));
typedef float f32x4 __attribute__((ext_vector_type(4)));

// bf16 helpers (finite values; RNE rounding)
static __device__ __forceinline__ unsigned short f2bf(float f) {
    unsigned int u = __float_as_uint(f);
    u = u + 0x7FFFu + ((u >> 16) & 1u);
    return (unsigned short)(u >> 16);
}
static __device__ __forceinline__ float bf2f(unsigned short h) {
    return __uint_as_float(((unsigned int)h) << 16);
}

// ---------------- CSR build ----------------

__global__ __launch_bounds__(256) void count_kernel(const int* __restrict__ dst,
        int* __restrict__ counts, int E) {
    int e = blockIdx.x * 256 + threadIdx.x;
    if (e < E) atomicAdd(&counts[dst[e]], 1);
}

__global__ __launch_bounds__(256) void scan_reduce(const int* __restrict__ counts,
        int* __restrict__ bsum, int n) {
    int b = blockIdx.x, t = threadIdx.x;
    int base = b * 1024 + t * 4;
    int s = 0;
    #pragma unroll
    for (int i = 0; i < 4; ++i) {
        int idx = base + i;
        if (idx < n) s += counts[idx];
    }
    __shared__ int sd[256];
    sd[t] = s;
    __syncthreads();
    #pragma unroll
    for (int off = 128; off > 0; off >>= 1) {
        if (t < off) sd[t] += sd[t + off];
        __syncthreads();
    }
    if (t == 0) bsum[b] = sd[0];
}

__global__ __launch_bounds__(64) void scan_tops(const int* __restrict__ bsum,
        int* __restrict__ bofs, int* __restrict__ row_ptr_end, int B) {
    int t = threadIdx.x;
    int v = (t < B) ? bsum[t] : 0;
    int inc = v;
    #pragma unroll
    for (int off = 1; off < 64; off <<= 1) {
        int u = __shfl_up(inc, off);
        if (t >= off) inc += u;
    }
    if (t < B) bofs[t] = inc - v;
    if (t == 63) *row_ptr_end = inc;
}

__global__ __launch_bounds__(256) void scan_final(const int* __restrict__ counts,
        const int* __restrict__ bofs, int* __restrict__ row_ptr,
        int* __restrict__ cursor, int n) {
    int b = blockIdx.x, t = threadIdx.x;
    int base = b * 1024 + t * 4;
    int v[4];
    int s = 0;
    #pragma unroll
    for (int i = 0; i < 4; ++i) {
        int idx = base + i;
        v[i] = (idx < n) ? counts[idx] : 0;
        s += v[i];
    }
    __shared__ int sd[256];
    sd[t] = s;
    __syncthreads();
    #pragma unroll
    for (int off = 1; off < 256; off <<= 1) {
        int u = (t >= off) ? sd[t - off] : 0;
        __syncthreads();
        sd[t] += u;
        __syncthreads();
    }
    int excl = bofs[b] + sd[t] - s;
    #pragma unroll
    for (int i = 0; i < 4; ++i) {
        int idx = base + i;
        if (idx < n) {
            row_ptr[idx] = excl;
            cursor[idx] = excl;
            excl += v[i];
        }
    }
}

__global__ __launch_bounds__(256) void fill_kernel(const int* __restrict__ src,
        const int* __restrict__ dst, int* __restrict__ cursor,
        int* __restrict__ src_sorted, int E) {
    int e = blockIdx.x * 256 + threadIdx.x;
    if (e < E) {
        int p = atomicAdd(&cursor[dst[e]], 1);
        src_sorted[p] = src[e];
    }
}

// ---------------- f32 -> bf16 bulk convert ----------------

__global__ __launch_bounds__(256) void cvt_kernel(const float* __restrict__ in,
        unsigned short* __restrict__ out, int n4) {
    int i = blockIdx.x * 256 + threadIdx.x;
    if (i < n4) {
        float4 v = ((const float4*)in)[i];
        ushort4 o;
        o.x = f2bf(v.x); o.y = f2bf(v.y); o.z = f2bf(v.z); o.w = f2bf(v.w);
        ((ushort4*)out)[i] = o;
    }
}

// ---------------- W pack: hi/lo bf16 split in MFMA B-fragment order ----------------
// B-frag for 16x16x32: lane l holds B[k0+j][n], n = ct*16 + (l&15),
// k0 = s*32 + (l>>4)*8, j=0..7. Packed: chunk ((s*8+ct)*2+hilo), 64 lanes x 16B.

__global__ __launch_bounds__(256) void pack_w(const float* __restrict__ W,
        unsigned short* __restrict__ Wp) {
    int t = blockIdx.x * 256 + threadIdx.x;   // 0..2047
    if (t >= 2048) return;
    int lane = t & 63;
    int ct = (t >> 6) & 7;
    int s = t >> 9;
    int n = ct * 16 + (lane & 15);
    int k0 = s * 32 + (lane >> 4) * 8;
    unsigned short hi[8], lo[8];
    #pragma unroll
    for (int j = 0; j < 8; ++j) {
        float f = W[(size_t)(k0 + j) * 128 + n];
        unsigned short h = f2bf(f);
        hi[j] = h;
        lo[j] = f2bf(f - bf2f(h));
    }
    size_t bh = ((size_t)((s * 8 + ct) * 2 + 0) * 64 + lane) * 8;
    size_t bl = ((size_t)((s * 8 + ct) * 2 + 1) * 64 + lane) * 8;
    #pragma unroll
    for (int j = 0; j < 8; ++j) { Wp[bh + j] = hi[j]; Wp[bl + j] = lo[j]; }
}

// ---------------- aggregation (batched over 2 graphs) ----------------

__global__ __launch_bounds__(256) void agg_kernel(const unsigned short* __restrict__ h,
        const int* __restrict__ row_ptr, const int* __restrict__ src_sorted,
        float* __restrict__ out, int N, int NT) {
    int node = blockIdx.x * 16 + (threadIdx.x >> 4);
    int lane = threadIdx.x & 15;
    if (node >= NT) return;
    int base = (node < N) ? 0 : N;
    int rp = node - base;
    int beg = row_ptr[rp], end = row_ptr[rp + 1];
    const uint4* h4 = (const uint4*)h;

    float acc[8];
    #pragma unroll
    for (int i = 0; i < 8; ++i) acc[i] = 0.f;

    auto addrow = [&](uint4 v) {
        acc[0] += __uint_as_float(v.x << 16);
        acc[1] += __uint_as_float(v.x & 0xFFFF0000u);
        acc[2] += __uint_as_float(v.y << 16);
        acc[3] += __uint_as_float(v.y & 0xFFFF0000u);
        acc[4] += __uint_as_float(v.z << 16);
        acc[5] += __uint_as_float(v.z & 0xFFFF0000u);
        acc[6] += __uint_as_float(v.w << 16);
        acc[7] += __uint_as_float(v.w & 0xFFFF0000u);
    };

    int j = beg;
    for (; j + 3 < end; j += 4) {
        int s0 = src_sorted[j] + base;
        int s1 = src_sorted[j + 1] + base;
        int s2 = src_sorted[j + 2] + base;
        int s3 = src_sorted[j + 3] + base;
        uint4 v0 = h4[(size_t)s0 * 16 + lane];
        uint4 v1 = h4[(size_t)s1 * 16 + lane];
        uint4 v2 = h4[(size_t)s2 * 16 + lane];
        uint4 v3 = h4[(size_t)s3 * 16 + lane];
        addrow(v0); addrow(v1); addrow(v2); addrow(v3);
    }
    for (; j < end; ++j) {
        int s0 = src_sorted[j] + base;
        addrow(h4[(size_t)s0 * 16 + lane]);
    }

    float4 f0 = make_float4(acc[0], acc[1], acc[2], acc[3]);
    float4 f1 = make_float4(acc[4], acc[5], acc[6], acc[7]);
    float4* o4 = (float4*)out;
    o4[(size_t)node * 32 + lane * 2]     = f0;
    o4[(size_t)node * 32 + lane * 2 + 1] = f1;
}

// ---------------- O_bf16 = relu(A @ W + b) via split-precision MFMA ----------------
// A f32 [M,128], split in-kernel to bf16 hi/lo. Wp prepacked hi/lo fragments.
// 3 MFMA per (k-step, col-tile): hi*hi + lo*hi + hi*lo ~= f32 product.
// Block = 256 thr = 4 waves x 16 rows; each wave does all 8 col-tiles.
// C/D mapping (m89-verified): col = lane&15, row = (lane>>4)*4 + reg.
// Optional fused column-mean over rows < Nmean (scaled by inv_n).

__global__ __launch_bounds__(256) void gemm_mfma(const float* __restrict__ A,
        const unsigned short* __restrict__ Wp, const float* __restrict__ bias,
        unsigned short* __restrict__ O, int M,
        float* __restrict__ mean_out, int Nmean, float inv_n) {
    __shared__ float red[4][128];
    int tid = threadIdx.x;
    int w = tid >> 6, l = tid & 63;
    int m0 = blockIdx.x * 64 + w * 16;
    int fr = l & 15;        // A-row within frag / C-col within tile
    int kg = l >> 4;        // k-group

    f32x4 acc[8];
    #pragma unroll
    for (int ct = 0; ct < 8; ++ct) acc[ct] = (f32x4){0.f, 0.f, 0.f, 0.f};

    int arow = m0 + fr; if (arow >= M) arow = M - 1;
    const float* abase = &A[(size_t)arow * 128 + kg * 8];
    const uint4* wp4 = (const uint4*)Wp;

    for (int s = 0; s < 4; ++s) {
        float4 a0 = *(const float4*)(abase + s * 32);
        float4 a1 = *(const float4*)(abase + s * 32 + 4);
        float av[8] = {a0.x, a0.y, a0.z, a0.w, a1.x, a1.y, a1.z, a1.w};
        bf16x8 a_hi, a_lo;
        #pragma unroll
        for (int j = 0; j < 8; ++j) {
            unsigned short h = f2bf(av[j]);
            a_hi[j] = (short)h;
            a_lo[j] = (short)f2bf(av[j] - bf2f(h));
        }
        #pragma unroll
        for (int ct = 0; ct < 8; ++ct) {
            uint4 bhu = wp4[(size_t)((s * 8 + ct) * 2 + 0) * 64 + l];
            uint4 blu = wp4[(size_t)((s * 8 + ct) * 2 + 1) * 64 + l];
            bf16x8 b_hi, b_lo;
            *(uint4*)&b_hi = bhu;
            *(uint4*)&b_lo = blu;
            acc[ct] = __builtin_amdgcn_mfma_f32_16x16x32_bf16(a_hi, b_hi, acc[ct], 0, 0, 0);
            acc[ct] = __builtin_amdgcn_mfma_f32_16x16x32_bf16(a_lo, b_hi, acc[ct], 0, 0, 0);
            acc[ct] = __builtin_amdgcn_mfma_f32_16x16x32_bf16(a_hi, b_lo, acc[ct], 0, 0, 0);
        }
    }

    float colsum[8];
    #pragma unroll
    for (int ct = 0; ct < 8; ++ct) {
        int col = ct * 16 + fr;
        float b = bias[col];
        float cs = 0.f;
        #pragma unroll
        for (int r = 0; r < 4; ++r) {
            int m = m0 + kg * 4 + r;
            float v = fmaxf(acc[ct][r] + b, 0.f);
            if (m < M) O[(size_t)m * 128 + col] = f2bf(v);
            if (m < Nmean) cs += v;
        }
        colsum[ct] = cs;
    }

    if (mean_out) {
        #pragma unroll
        for (int ct = 0; ct < 8; ++ct) {
            float v = colsum[ct];
            v += __shfl_xor(v, 16);
            v += __shfl_xor(v, 32);
            if (l < 16) red[w][ct * 16 + l] = v;
        }
        __syncthreads();
        if (tid < 128) {
            float s = red[0][tid] + red[1][tid] + red[2][tid] + red[3][tid];
            if (s != 0.f) atomicAdd(&mean_out[tid], s * inv_n);
        }
    }
}

// ---------------- wsv = Wd @ s ----------------

__global__ __launch_bounds__(128) void wd_kernel(const float* __restrict__ Wd,
        const float* __restrict__ s, float* __restrict__ wsv) {
    __shared__ float sl[128];
    int i = threadIdx.x;
    sl[i] = s[i];
    __syncthreads();
    float acc = 0.f;
    for (int j = 0; j < 128; ++j) acc += Wd[(size_t)i * 128 + j] * sl[j];
    wsv[i] = acc;
}

// ---------------- out[i] = dot(h[i], wsv), h bf16, one wave per node ----------------

__global__ __launch_bounds__(256) void disc_kernel(const unsigned short* __restrict__ h,
        const float* __restrict__ wsv, float* __restrict__ out, int n) {
    int wave = threadIdx.x >> 6, lane = threadIdx.x & 63;
    int node = blockIdx.x * 4 + wave;
    if (node >= n) return;
    unsigned int hv = ((const unsigned int*)h)[(size_t)node * 64 + lane];
    float2 wv = *(const float2*)&wsv[lane * 2];
    float lo = __uint_as_float(hv << 16);
    float hi = __uint_as_float(hv & 0xFFFF0000u);
    float acc = lo * wv.x + hi * wv.y;
    #pragma unroll
    for (int off = 32; off > 0; off >>= 1) acc += __shfl_down(acc, off);
    if (lane == 0) out[node] = acc;
}

// ---------------- host orchestration ----------------

extern "C" void kernel_launch(void* const* d_in, const int* in_sizes, int n_in,
                              void* d_out, int out_size, void* d_ws, size_t ws_size,
                              hipStream_t stream) {
    const int* edge_index = (const int*)d_in[0];
    const float* x  = (const float*)d_in[1];
    const float* sx = (const float*)d_in[2];
    const float* W0 = (const float*)d_in[3];
    const float* b0 = (const float*)d_in[4];
    const float* W1 = (const float*)d_in[5];
    const float* b1 = (const float*)d_in[6];
    const float* W2 = (const float*)d_in[7];
    const float* b2 = (const float*)d_in[8];
    const float* Wd = (const float*)d_in[9];
    float* out = (float*)d_out;

    const int E = in_sizes[0] / 2;
    const int N = in_sizes[1] / D;
    const int* src = edge_index;
    const int* dst = edge_index + E;
    const float inv_n = 1.0f / (float)N;

    char* wsp = (char*)d_ws;
    size_t off = 0;
    auto alloc = [&](size_t bytes) -> void* {
        void* p = wsp + off;
        off += (bytes + 511) & ~(size_t)511;
        return p;
    };
    int* counts     = (int*)alloc((size_t)N * 4);
    int* row_ptr    = (int*)alloc((size_t)(N + 1) * 4);
    int* cursor     = (int*)alloc((size_t)N * 4);
    int* src_sorted = (int*)alloc((size_t)E * 4);
    int* bsum       = (int*)alloc(64 * 4);
    int* bofs       = (int*)alloc(64 * 4);
    float* svec     = (float*)alloc(D * 4);
    float* wsv      = (float*)alloc(D * 4);
    unsigned short* wp0 = (unsigned short*)alloc((size_t)D * D * 2 * 2);
    unsigned short* wp1 = (unsigned short*)alloc((size_t)D * D * 2 * 2);
    unsigned short* wp2 = (unsigned short*)alloc((size_t)D * D * 2 * 2);

    size_t fixed = off;
    size_t need_batched = fixed + ((size_t)2 * N * D * 4 + 512) + ((size_t)2 * N * D * 2 + 512);
    bool batched = ws_size >= need_batched;
    int NB = batched ? 2 * N : N;

    float* aggbuf        = (float*)alloc((size_t)NB * D * 4);
    unsigned short* hbuf = (unsigned short*)alloc((size_t)NB * D * 2);

    hipMemsetAsync(counts, 0, (size_t)N * 4, stream);
    hipMemsetAsync(svec, 0, D * 4, stream);

    pack_w<<<8, 256, 0, stream>>>(W0, wp0);
    pack_w<<<8, 256, 0, stream>>>(W1, wp1);
    pack_w<<<8, 256, 0, stream>>>(W2, wp2);

    int eblocks = (E + 255) / 256;
    int sblocks = (N + 1023) / 1024;
    count_kernel<<<eblocks, 256, 0, stream>>>(dst, counts, E);
    scan_reduce<<<sblocks, 256, 0, stream>>>(counts, bsum, N);
    scan_tops<<<1, 64, 0, stream>>>(bsum, bofs, row_ptr + N, sblocks);
    scan_final<<<sblocks, 256, 0, stream>>>(counts, bofs, row_ptr, cursor, N);
    fill_kernel<<<eblocks, 256, 0, stream>>>(src, dst, cursor, src_sorted, E);

    int n4 = N * D / 4;
    int cblocks = (n4 + 255) / 256;
    int ablocks = (NB + 15) / 16;
    int gblocks = (NB + 63) / 64;

    if (batched) {
        cvt_kernel<<<cblocks, 256, 0, stream>>>(x, hbuf, n4);
        cvt_kernel<<<cblocks, 256, 0, stream>>>(sx, hbuf + (size_t)N * D, n4);
        agg_kernel<<<ablocks, 256, 0, stream>>>(hbuf, row_ptr, src_sorted, aggbuf, N, NB);
        gemm_mfma<<<gblocks, 256, 0, stream>>>(aggbuf, wp0, b0, hbuf, NB, nullptr, 0, 0.f);
        agg_kernel<<<ablocks, 256, 0, stream>>>(hbuf, row_ptr, src_sorted, aggbuf, N, NB);
        gemm_mfma<<<gblocks, 256, 0, stream>>>(aggbuf, wp1, b1, hbuf, NB, nullptr, 0, 0.f);
        agg_kernel<<<ablocks, 256, 0, stream>>>(hbuf, row_ptr, src_sorted, aggbuf, N, NB);
        gemm_mfma<<<gblocks, 256, 0, stream>>>(aggbuf, wp2, b2, hbuf, NB, svec, N, inv_n);
        wd_kernel<<<1, 128, 0, stream>>>(Wd, svec, wsv);
        disc_kernel<<<(NB + 3) / 4, 256, 0, stream>>>(hbuf, wsv, out, NB);
    } else {
        auto encode = [&](const float* input, float* mean_out) {
            cvt_kernel<<<cblocks, 256, 0, stream>>>(input, hbuf, n4);
            agg_kernel<<<ablocks, 256, 0, stream>>>(hbuf, row_ptr, src_sorted, aggbuf, N, NB);
            gemm_mfma<<<gblocks, 256, 0, stream>>>(aggbuf, wp0, b0, hbuf, NB, nullptr, 0, 0.f);
            agg_kernel<<<ablocks, 256, 0, stream>>>(hbuf, row_ptr, src_sorted, aggbuf, N, NB);
            gemm_mfma<<<gblocks, 256, 0, stream>>>(aggbuf, wp1, b1, hbuf, NB, nullptr, 0, 0.f);
            agg_kernel<<<ablocks, 256, 0, stream>>>(hbuf, row_ptr, src_sorted, aggbuf, N, NB);
            gemm_mfma<<<gblocks, 256, 0, stream>>>(aggbuf, wp2, b2, hbuf, NB, mean_out, mean_out ? N : 0, inv_n);
        };
        encode(x, svec);
        wd_kernel<<<1, 128, 0, stream>>>(Wd, svec, wsv);
        disc_kernel<<<(NB + 3) / 4, 256, 0, stream>>>(hbuf, wsv, out, NB);
        encode(sx, nullptr);
        disc_kernel<<<(NB + 3) / 4, 256, 0, stream>>>(hbuf, wsv, out + N, NB);
    }
}